// Round 3
// baseline (86.240 us; speedup 1.0000x reference)
//
#include <hip/hip_runtime.h>
#include <hip/hip_bf16.h>
#include <math.h>

// Problem constants (from reference): x shape (32, 512, 56, 56) fp32,
// groups shape (G, 4) int32 (partition of channels, -1 padded).
#define NB 32
#define CC 512
#define HW 3136       // 56*56
#define HW8 392       // HW/8, 8-float (2x float4) granularity
#define SMAX 4

typedef float f32x4 __attribute__((ext_vector_type(4)));  // native vector: nontemporal-builtin-compatible

// One thread: one (n, group, pixel8). Reads up to 4 channels x 2 float4
// (non-temporal: zero-reuse streaming, bypass L2 allocation), per-lane
// argmax (strict >, first occurrence wins like jnp.argmax), writes winner
// value / zeros with non-temporal stores. Groups partition C, so every
// output element is written exactly once.
__global__ __launch_bounds__(256) void cgm_kernel(
    const float* __restrict__ x,
    const int* __restrict__ groups,
    float* __restrict__ out,
    int G)
{
    int idx = blockIdx.x * blockDim.x + threadIdx.x;
    int total = NB * G * HW8;
    if (idx >= total) return;

    int p8 = idx % HW8;          // which 8-float chunk within the HW plane
    int ng = idx / HW8;
    int g  = ng % G;
    int n  = ng / G;

    // group channel indices (wave-mostly-uniform, tiny, L2-resident)
    int ch[SMAX];
#pragma unroll
    for (int s = 0; s < SMAX; ++s) ch[s] = groups[g * SMAX + s];

    size_t nbase = (size_t)n * CC * HW + (size_t)p8 * 8;

    float v[SMAX][8];
#pragma unroll
    for (int s = 0; s < SMAX; ++s) {
        if (ch[s] >= 0) {
            const f32x4* p = reinterpret_cast<const f32x4*>(x + nbase + (size_t)ch[s] * HW);
            f32x4 t0 = __builtin_nontemporal_load(p);
            f32x4 t1 = __builtin_nontemporal_load(p + 1);
            v[s][0] = t0.x; v[s][1] = t0.y; v[s][2] = t0.z; v[s][3] = t0.w;
            v[s][4] = t1.x; v[s][5] = t1.y; v[s][6] = t1.z; v[s][7] = t1.w;
        } else {
#pragma unroll
            for (int j = 0; j < 8; ++j) v[s][j] = -INFINITY;
        }
    }

    // per-lane argmax over s (first occurrence of max wins)
    int win[8];
#pragma unroll
    for (int j = 0; j < 8; ++j) {
        float best = v[0][j];
        int   wi   = 0;
#pragma unroll
        for (int s = 1; s < SMAX; ++s) {
            if (v[s][j] > best) { best = v[s][j]; wi = s; }
        }
        win[j] = wi;
    }

#pragma unroll
    for (int s = 0; s < SMAX; ++s) {
        if (ch[s] >= 0) {
            f32x4 o0, o1;
            o0.x = (win[0] == s) ? v[s][0] : 0.0f;
            o0.y = (win[1] == s) ? v[s][1] : 0.0f;
            o0.z = (win[2] == s) ? v[s][2] : 0.0f;
            o0.w = (win[3] == s) ? v[s][3] : 0.0f;
            o1.x = (win[4] == s) ? v[s][4] : 0.0f;
            o1.y = (win[5] == s) ? v[s][5] : 0.0f;
            o1.z = (win[6] == s) ? v[s][6] : 0.0f;
            o1.w = (win[7] == s) ? v[s][7] : 0.0f;
            f32x4* q = reinterpret_cast<f32x4*>(out + nbase + (size_t)ch[s] * HW);
            __builtin_nontemporal_store(o0, q);
            __builtin_nontemporal_store(o1, q + 1);
        }
    }
}

extern "C" void kernel_launch(void* const* d_in, const int* in_sizes, int n_in,
                              void* d_out, int out_size, void* d_ws, size_t ws_size,
                              hipStream_t stream) {
    const float* x      = (const float*)d_in[0];
    const int*   groups = (const int*)d_in[1];
    float*       out    = (float*)d_out;

    int G = in_sizes[1] / SMAX;   // 147 for this problem
    int total = NB * G * HW8;     // 1,843,968
    int block = 256;
    int grid = (total + block - 1) / block;  // 7203 blocks

    cgm_kernel<<<grid, block, 0, stream>>>(x, groups, out, G);
}

// Round 4
// 69.092 us; speedup vs baseline: 1.2482x; 1.2482x over previous
//
#include <hip/hip_runtime.h>
#include <hip/hip_bf16.h>
#include <math.h>

// Problem constants (from reference): x shape (32, 512, 56, 56) fp32,
// groups shape (G, 4) int32 (partition of channels, -1 padded).
#define NB 32
#define CC 512
#define HW 3136       // 56*56
#define HW4 784       // HW/4, float4 granularity
#define SMAX 4

typedef float f32x4 __attribute__((ext_vector_type(4)));  // native vector: nontemporal-builtin-compatible

// One thread: one (n, group, pixel4). Lane i at byte 16*i of each channel
// plane -> each 64-lane load/store instruction is one contiguous, fully
// consumed 1 KB segment. Non-temporal (zero reuse -> don't pollute L2).
// Per-lane argmax (strict >, first occurrence wins like jnp.argmax).
// Groups partition C, so every output element is written exactly once.
__global__ __launch_bounds__(256) void cgm_kernel(
    const float* __restrict__ x,
    const int* __restrict__ groups,
    float* __restrict__ out,
    int G)
{
    int idx = blockIdx.x * blockDim.x + threadIdx.x;
    int total = NB * G * HW4;
    if (idx >= total) return;

    int p4 = idx % HW4;          // which float4 within the HW plane
    int ng = idx / HW4;
    int g  = ng % G;
    int n  = ng / G;

    // group channel indices (wave-mostly-uniform, tiny, L2-resident)
    int ch[SMAX];
#pragma unroll
    for (int s = 0; s < SMAX; ++s) ch[s] = groups[g * SMAX + s];

    size_t nbase = (size_t)n * CC * HW + (size_t)p4 * 4;

    float v[SMAX][4];
#pragma unroll
    for (int s = 0; s < SMAX; ++s) {
        if (ch[s] >= 0) {
            const f32x4* p = reinterpret_cast<const f32x4*>(x + nbase + (size_t)ch[s] * HW);
            f32x4 t = __builtin_nontemporal_load(p);
            v[s][0] = t.x; v[s][1] = t.y; v[s][2] = t.z; v[s][3] = t.w;
        } else {
#pragma unroll
            for (int j = 0; j < 4; ++j) v[s][j] = -INFINITY;
        }
    }

    // per-lane argmax over s (first occurrence of max wins)
    int win[4];
#pragma unroll
    for (int j = 0; j < 4; ++j) {
        float best = v[0][j];
        int   wi   = 0;
#pragma unroll
        for (int s = 1; s < SMAX; ++s) {
            if (v[s][j] > best) { best = v[s][j]; wi = s; }
        }
        win[j] = wi;
    }

#pragma unroll
    for (int s = 0; s < SMAX; ++s) {
        if (ch[s] >= 0) {
            f32x4 o;
            o.x = (win[0] == s) ? v[s][0] : 0.0f;
            o.y = (win[1] == s) ? v[s][1] : 0.0f;
            o.z = (win[2] == s) ? v[s][2] : 0.0f;
            o.w = (win[3] == s) ? v[s][3] : 0.0f;
            f32x4* q = reinterpret_cast<f32x4*>(out + nbase + (size_t)ch[s] * HW);
            __builtin_nontemporal_store(o, q);
        }
    }
}

extern "C" void kernel_launch(void* const* d_in, const int* in_sizes, int n_in,
                              void* d_out, int out_size, void* d_ws, size_t ws_size,
                              hipStream_t stream) {
    const float* x      = (const float*)d_in[0];
    const int*   groups = (const int*)d_in[1];
    float*       out    = (float*)d_out;

    int G = in_sizes[1] / SMAX;   // 147 for this problem
    int total = NB * G * HW4;     // 3,687,936
    int block = 256;
    int grid = (total + block - 1) / block;  // 14,406 blocks

    cgm_kernel<<<grid, block, 0, stream>>>(x, groups, out, G);
}